// Round 10
// baseline (183.938 us; speedup 1.0000x reference)
//
#include <hip/hip_runtime.h>

// ---- problem constants (from reference setup_inputs) ----
constexpr int cS = 16, cN = 64, cH = 200, cW = 240;
constexpr int cHC = 25, cWC = 30;          // coarse fmap (stride 8)
constexpr int cHF = 100, cWF = 120;        // fine fmap (stride 2)
constexpr int cC = 64;                     // LAT
constexpr int cITERS = 4;                  // setup_inputs fixed
constexpr int cNCH = 50, cCHUNK = 60;      // ffw split

typedef _Float16 half8 __attribute__((ext_vector_type(8)));
typedef _Float16 h2 __attribute__((ext_vector_type(2)));

// NOTE (round 7 lesson): hipLaunchCooperativeKernel fails under this harness's
// graph capture (output never written). Stay with normal stream launches.
// NOTE (round 9 lesson): k_front/k_iter are latency-bound, not VALU-bound;
// the k_iter GEMV is L2-BW on LWc -> amortize it across rows per block.

// ---------------------------------------------------------------------------
// helpers
// ---------------------------------------------------------------------------
__device__ __forceinline__ float bilin_raw_h(const _Float16* __restrict__ fm, int Hh, int Ww,
                                             float x, float y, int c, float& wsum) {
  x = fminf(fmaxf(x, -2.0e6f), 2.0e6f);
  y = fminf(fmaxf(y, -2.0e6f), 2.0e6f);
  float x0f = floorf(x), y0f = floorf(y);
  int ix = (int)x0f, iy = (int)y0f;
  float wx = x - x0f, wy = y - y0f;
  float acc = 0.f; wsum = 0.f;
  bool vx0 = (ix >= 0) && (ix < Ww), vx1 = (ix + 1 >= 0) && (ix + 1 < Ww);
  bool vy0 = (iy >= 0) && (iy < Hh), vy1 = (iy + 1 >= 0) && (iy + 1 < Hh);
  float w00 = (1.f - wy) * (1.f - wx), w01 = (1.f - wy) * wx;
  float w10 = wy * (1.f - wx), w11 = wy * wx;
  if (vy0 && vx0) { acc += (float)fm[(iy * Ww + ix) * cC + c] * w00; wsum += w00; }
  if (vy0 && vx1) { acc += (float)fm[(iy * Ww + ix + 1) * cC + c] * w01; wsum += w01; }
  if (vy1 && vx0) { acc += (float)fm[((iy + 1) * Ww + ix) * cC + c] * w10; wsum += w10; }
  if (vy1 && vx1) { acc += (float)fm[((iy + 1) * Ww + ix + 1) * cC + c] * w11; wsum += w11; }
  return acc;
}

// ---------------------------------------------------------------------------
// k_front: role-partitioned. [0,800) ffp; [800,1200) convc (row-blocks);
// [1200,2800) convf.
// ---------------------------------------------------------------------------
constexpr int NB_FFP = 800, NB_CONVC = 400, NB_CONVF = 1600;

__global__ __launch_bounds__(256) void k_front(const float* __restrict__ rgbs,
                                               const float* __restrict__ w1s,
                                               const float* __restrict__ w1t,
                                               const float* __restrict__ fnw,
                                               const float* __restrict__ fnfw,
                                               float* __restrict__ part,
                                               _Float16* __restrict__ fmc,
                                               float* __restrict__ partc,
                                               _Float16* __restrict__ fmf,
                                               float* __restrict__ partf) {
  __shared__ float smem[6528];
  int bid = blockIdx.x, tid = threadIdx.x;
  const float a = 2.0f / 255.0f;

  if (bid < NB_FFP) {
    int s = bid / cNCH, ch = bid % cNCH;
    if (tid < cCHUNK) {
      const float* cur = rgbs + (size_t)s * cH * cW;
      const float* prev = rgbs + (size_t)(s - 1) * cH * cW;
      const float* last = rgbs + (size_t)15 * cH * cW;
      int y = 4 * ch + 1, x = 4 * tid + 1;
      float v = 0.f;
      #pragma unroll
      for (int dy = 0; dy < 2; dy++)
        #pragma unroll
        for (int dx = 0; dx < 2; dx++) {
          int id = (y + dy) * cW + (x + dx);
          float pv = (s == 0) ? (a * last[id] - 1.0f) : (a * (cur[id] - prev[id]));
          v += pv;
        }
      smem[tid] = 0.25f * v;
    }
    __syncthreads();
    int t = tid >> 7, j = tid & 127;
    const float* w = (t == 0) ? (w1s + (size_t)198 * 128) : (w1t + (size_t)394 * 128);
    const float* wr = w + (size_t)ch * cCHUNK * 128 + j;
    float acc = 0.f;
    #pragma unroll 4
    for (int i = 0; i < cCHUNK; i++) acc += smem[i] * wr[(size_t)i * 128];
    part[(((size_t)t * cS + s) * cNCH + ch) * 128 + j] = acc;

  } else if (bid < NB_FFP + NB_CONVC) {
    int idx = bid - NB_FFP;
    int q = idx / 25, y = idx % 25;
    float* imgL = smem;           // [1920] = 8 rows x 240
    float* wlT = smem + 1920;     // [4096] transposed weights [tap][c]
    float* red = smem + 6016;     // [512]
    const float* img = rgbs + ((size_t)q * cH + y * 8) * cW;
    for (int i = tid; i < 1920; i += 256) imgL[i] = img[i];
    for (int i = tid; i < 4096; i += 256) {
      int tap = i >> 6, c = i & 63;
      wlT[i] = fnw[c * 64 + tap];
    }
    __syncthreads();
    int c = tid & 63, g = tid >> 6;
    float wsum = 0.f;
    for (int t = 0; t < 64; t++) wsum += wlT[t * 64 + c];
    float sum = 0.f, ss = 0.f;
    for (int x = g; x < 30; x += 4) {
      float acc = 0.f;
      #pragma unroll
      for (int ky = 0; ky < 8; ky++)
        #pragma unroll
        for (int kx = 0; kx < 8; kx++)
          acc += wlT[(ky * 8 + kx) * 64 + c] * imgL[ky * 240 + x * 8 + kx];
      float v = a * acc - wsum;   // b = -1 folded: conv(2p/255 - 1)
      fmc[((size_t)q * 750 + y * 30 + x) * cC + c] = (_Float16)v;
      sum += v; ss += v * v;
    }
    red[(0 * 4 + g) * 64 + c] = sum;
    red[(1 * 4 + g) * 64 + c] = ss;
    __syncthreads();
    if (g == 0) {
      float s4 = red[0 * 64 + c] + red[1 * 64 + c] + red[2 * 64 + c] + red[3 * 64 + c];
      float q4 = red[(4 + 0) * 64 + c] + red[(4 + 1) * 64 + c] +
                 red[(4 + 2) * 64 + c] + red[(4 + 3) * 64 + c];
      size_t o = ((size_t)q * 25 + y) * 64 + c;
      partc[o * 2 + 0] = s4;
      partc[o * 2 + 1] = q4;
    }

  } else {
    int idx = bid - NB_FFP - NB_CONVC;
    int q = idx / cHF, y = idx % cHF;
    int lane = tid & 63, wv = tid >> 6;
    float w0 = fnfw[lane * 4 + 0], w1 = fnfw[lane * 4 + 1];
    float w2 = fnfw[lane * 4 + 2], w3 = fnfw[lane * 4 + 3];
    float wsum = w0 + w1 + w2 + w3;
    const float* img = rgbs + (size_t)q * cH * cW;
    float sum = 0.f, ss = 0.f;
    for (int x = wv; x < cWF; x += 4) {
      const float* b = img + (2 * y) * cW + 2 * x;
      float v = a * (w0 * b[0] + w1 * b[1] + w2 * b[cW] + w3 * b[cW + 1]) - wsum;
      fmf[(((size_t)q * cHF + y) * cWF + x) * cC + lane] = (_Float16)v;
      sum += v; ss += v * v;
    }
    float* red = smem;
    red[(0 * 4 + wv) * 64 + lane] = sum;
    red[(1 * 4 + wv) * 64 + lane] = ss;
    __syncthreads();
    if (wv == 0) {
      float s4 = red[0 * 64 + lane] + red[1 * 64 + lane] + red[2 * 64 + lane] + red[3 * 64 + lane];
      float q4 = red[(4 + 0) * 64 + lane] + red[(4 + 1) * 64 + lane] +
                 red[(4 + 2) * 64 + lane] + red[(4 + 3) * 64 + lane];
      size_t o = ((size_t)q * cHF + y) * 64 + lane;
      partf[o * 2 + 0] = s4;
      partf[o * 2 + 1] = q4;
    }
  }
}

// ---------------------------------------------------------------------------
// k_mid: [0,16) ffw_red; [16,91) LWc (pair-packed fp16) + b1te; [91,107) fine
// stats; [107,123) coarse stats; [123,139) coarse pyramid + RAW arp;
// [139,347) fine pyramid (needs only fmf from k_front).
// ---------------------------------------------------------------------------
__global__ __launch_bounds__(256) void k_mid(const float* __restrict__ part,
                                             float* __restrict__ ffw_s, float* __restrict__ ffw_t,
                                             const float* __restrict__ lw, const float* __restrict__ lb,
                                             const float* __restrict__ w1t, const float* __restrict__ b1t,
                                             h2* __restrict__ LWc2, float* __restrict__ b1te,
                                             const float* __restrict__ partf, float* __restrict__ stats,
                                             const float* __restrict__ partc, float* __restrict__ statc,
                                             const _Float16* __restrict__ fmc, float* __restrict__ arp,
                                             const _Float16* __restrict__ fmf,
                                             _Float16* __restrict__ pf1, _Float16* __restrict__ pf2,
                                             _Float16* __restrict__ pf3) {
  __shared__ float smem[14784];
  int bid = blockIdx.x, tid = threadIdx.x;

  if (bid < 16) {
    int s = bid, t = tid >> 7, j = tid & 127;
    const float* p = part + (((size_t)t * cS + s) * cNCH) * 128 + j;
    float acc = 0.f;
    for (int c = 0; c < cNCH; c++) acc += p[(size_t)c * 128];
    ((t == 0) ? ffw_s : ffw_t)[s * 128 + j] = acc;

  } else if (bid < 91) {
    int b2 = bid - 16, g = tid >> 7, j = tid & 127;
    if (b2 < 74) {
      int k0 = b2 * 8 + g * 4;
      if (k0 < 588) {
        const float* l0 = lw + (size_t)(k0 + 0) * 392;
        const float* l1 = lw + (size_t)(k0 + 1) * 392;
        const float* l2 = lw + (size_t)(k0 + 2) * 392;
        const float* l3 = lw + (size_t)(k0 + 3) * 392;
        float a0 = 0.f, a1 = 0.f, a2 = 0.f, a3 = 0.f;
        for (int m = 0; m < 392; m++) {
          float wv = w1t[(size_t)m * 128 + j];
          a0 += l0[m] * wv; a1 += l1[m] * wv; a2 += l2[m] * wv; a3 += l3[m] * wv;
        }
        int kk = k0 >> 1;   // pair-packed: LWc2[(k/2)*128+j] = {LWc[k],LWc[k+1]}
        LWc2[(size_t)(kk + 0) * 128 + j] = h2{(_Float16)a0, (_Float16)a1};
        LWc2[(size_t)(kk + 1) * 128 + j] = h2{(_Float16)a2, (_Float16)a3};
      }
    } else if (g == 0) {
      float acc = b1t[j];
      for (int m = 0; m < 392; m++) acc += lb[m] * w1t[(size_t)m * 128 + j];
      b1te[j] = acc;
    }

  } else if (bid < 107) {
    int q = bid - 91, c = tid & 63, g = tid >> 6;
    float s0 = 0.f, s1 = 0.f;
    for (int yy = 0; yy < 25; yy++) {
      size_t o = ((size_t)q * cHF + g * 25 + yy) * 64 + c;
      s0 += partf[o * 2 + 0];
      s1 += partf[o * 2 + 1];
    }
    smem[g * 64 + c] = s0;
    smem[256 + g * 64 + c] = s1;
    __syncthreads();
    if (g == 0) {
      stats[(q * 64 + c) * 2 + 0] = smem[c] + smem[64 + c] + smem[128 + c] + smem[192 + c];
      stats[(q * 64 + c) * 2 + 1] = smem[256 + c] + smem[320 + c] + smem[384 + c] + smem[448 + c];
    }

  } else if (bid < 123) {
    int q = bid - 107, c = tid & 63, g = tid >> 6;
    float s0 = 0.f, s1 = 0.f;
    for (int yy = g; yy < 25; yy += 4) {
      size_t o = ((size_t)q * 25 + yy) * 64 + c;
      s0 += partc[o * 2 + 0];
      s1 += partc[o * 2 + 1];
    }
    smem[g * 64 + c] = s0;
    smem[256 + g * 64 + c] = s1;
    __syncthreads();
    if (g == 0) {
      statc[(q * 64 + c) * 2 + 0] = smem[c] + smem[64 + c] + smem[128 + c] + smem[192 + c];
      statc[(q * 64 + c) * 2 + 1] = smem[256 + c] + smem[320 + c] + smem[384 + c] + smem[448 + c];
    }

  } else if (bid < 139) {
    // ---- coarse pyramid (3 pools in LDS) + RAW averaged-resize arp ----
    int q = bid - 123;
    float* pc1 = smem;            // 12*15*64
    float* pc2 = smem + 11520;    // 6*7*64
    float* pc3 = smem + 14208;    // 3*3*64
    const _Float16* L0 = fmc + (size_t)q * 750 * cC;
    for (int i = tid; i < 12 * 15 * 64; i += 256) {
      int c = i & 63, pos = i >> 6, oy = pos / 15, ox = pos % 15;
      const _Float16* b = L0 + ((2 * oy) * 30 + 2 * ox) * cC + c;
      pc1[i] = 0.25f * ((float)b[0] + (float)b[cC] + (float)b[30 * cC] + (float)b[30 * cC + cC]);
    }
    __syncthreads();
    for (int i = tid; i < 6 * 7 * 64; i += 256) {
      int c = i & 63, pos = i >> 6, oy = pos / 7, ox = pos % 7;
      const float* b = pc1 + ((2 * oy) * 15 + 2 * ox) * cC + c;
      pc2[i] = 0.25f * (b[0] + b[cC] + b[15 * cC] + b[15 * cC + cC]);
    }
    __syncthreads();
    for (int i = tid; i < 3 * 3 * 64; i += 256) {
      int c = i & 63, pos = i >> 6, oy = pos / 3, ox = pos % 3;
      const float* b = pc2 + ((2 * oy) * 7 + 2 * ox) * cC + c;
      pc3[i] = 0.25f * (b[0] + b[cC] + b[7 * cC] + b[7 * cC + cC]);
    }
    __syncthreads();
    const int Hs[4] = {25, 12, 6, 3}, Ws[4] = {30, 15, 7, 3};
    for (int i = tid; i < 196 * 64; i += 256) {
      int c = i & 63, pos = i >> 6, o = pos / 14, p = pos % 14;
      float acc = 0.f;
      #pragma unroll
      for (int l = 0; l < 4; l++) {
        float yy = (float)(o * (Hs[l] - 1)) / 13.0f;
        float xx = (float)(p * (Ws[l] - 1)) / 13.0f;
        int y0 = (int)floorf(yy); int y1 = min(y0 + 1, Hs[l] - 1); float wy = yy - (float)y0;
        int x0 = (int)floorf(xx); int x1 = min(x0 + 1, Ws[l] - 1); float wx = xx - (float)x0;
        float v00, v01, v10, v11;
        if (l == 0) {
          v00 = (float)L0[(y0 * 30 + x0) * cC + c]; v01 = (float)L0[(y0 * 30 + x1) * cC + c];
          v10 = (float)L0[(y1 * 30 + x0) * cC + c]; v11 = (float)L0[(y1 * 30 + x1) * cC + c];
        } else {
          const float* L = (l == 1) ? pc1 : ((l == 2) ? pc2 : pc3);
          int Wl = Ws[l];
          v00 = L[(y0 * Wl + x0) * cC + c]; v01 = L[(y0 * Wl + x1) * cC + c];
          v10 = L[(y1 * Wl + x0) * cC + c]; v11 = L[(y1 * Wl + x1) * cC + c];
        }
        acc += (v00 * (1.f - wy) + v10 * wy) * (1.f - wx) + (v01 * (1.f - wy) + v11 * wy) * wx;
      }
      arp[((size_t)q * 196 + pos) * cC + c] = acc * 0.25f * 0.125f;  // RAW (norm folded at use)
    }

  } else {
    // ---- fine pyramid ----
    int u = bid - 139;
    int q = u / 13, b = u % 13;
    _Float16* l1 = (_Float16*)smem;     // [4*60*64]
    _Float16* l2 = l1 + 15360;          // [2*30*64]
    int nr1 = (b == 12) ? 2 : 4;
    const _Float16* F = fmf + (size_t)q * cHF * cWF * cC;
    for (int i = tid; i < nr1 * 60 * 64; i += 256) {
      int c = i & 63, pos = i >> 6, rl = pos / 60, ox = pos % 60;
      int r1 = 4 * b + rl;
      const _Float16* p = F + ((size_t)(2 * r1) * cWF + 2 * ox) * cC + c;
      float v = 0.25f * ((float)p[0] + (float)p[cC] + (float)p[cWF * cC] + (float)p[cWF * cC + cC]);
      _Float16 h = (_Float16)v;
      l1[i] = h;
      pf1[(((size_t)q * 50 + r1) * 60 + ox) * cC + c] = h;
    }
    __syncthreads();
    int nr2 = (b == 12) ? 1 : 2;
    for (int i = tid; i < nr2 * 30 * 64; i += 256) {
      int c = i & 63, pos = i >> 6, rl = pos / 30, ox = pos % 30;
      const _Float16* p = l1 + ((2 * rl) * 60 + 2 * ox) * 64 + c;
      float v = 0.25f * ((float)p[0] + (float)p[64] + (float)p[60 * 64] + (float)p[60 * 64 + 64]);
      _Float16 h = (_Float16)v;
      l2[i] = h;
      pf2[(((size_t)q * 25 + 2 * b + rl) * 30 + ox) * cC + c] = h;
    }
    __syncthreads();
    if (b < 12) {
      for (int i = tid; i < 15 * 64; i += 256) {
        int c = i & 63, ox = i >> 6;
        const _Float16* p = l2 + (2 * ox) * 64 + c;
        float v = 0.25f * ((float)p[0] + (float)p[64] + (float)p[30 * 64] + (float)p[30 * 64 + 64]);
        pf3[(((size_t)q * 12 + b) * 15 + ox) * cC + c] = (_Float16)v;
      }
    }
  }
}

// ---------------------------------------------------------------------------
// k_mix: coarse MLP only (norm affine folded into featc+bias). 256 blocks.
// ---------------------------------------------------------------------------
__global__ __launch_bounds__(256) void k_mix(const float* __restrict__ arp, const _Float16* __restrict__ fmc,
                                             const float* __restrict__ statc,
                                             const float* __restrict__ w1, const float* __restrict__ b1,
                                             const float* __restrict__ ffw, const float* __restrict__ w2,
                                             const float* __restrict__ b2, const float* __restrict__ pts,
                                             float* __restrict__ cof, float* __restrict__ xys,
                                             float* __restrict__ out) {
  __shared__ float fc[784];
  __shared__ float f0n[64];
  __shared__ float featc[256];
  __shared__ float biasc[4];
  __shared__ float hp[1024];
  __shared__ float hl[512];
  int bid = blockIdx.x, tid = threadIdx.x;

  int n = bid >> 2, sb = (bid & 3) * 4;
  float xx = pts[n * 2 + 0] * 0.125f, yy = pts[n * 2 + 1] * 0.125f;
  if (tid < 64) {
    float ws;
    float raw = bilin_raw_h(fmc, cHC, cWC, xx, yy, tid, ws);
    float mu = statc[tid * 2 + 0] / 750.f;                 // frame 0
    float var = statc[tid * 2 + 1] / 750.f - mu * mu;
    float r0 = rsqrtf(var + 1e-5f);
    f0n[tid] = r0 * (raw - mu * ws);
  }
  __syncthreads();
  {
    int rr = tid >> 6, c = tid & 63;
    int s = sb + rr;
    float mu = statc[(s * 64 + c) * 2 + 0] / 750.f;
    float var = statc[(s * 64 + c) * 2 + 1] / 750.f - mu * mu;
    float rs = rsqrtf(var + 1e-5f);
    float fv = rs * f0n[c];
    featc[rr * 64 + c] = fv;
    float bc = -0.25f * 0.125f * mu * fv;
    #pragma unroll
    for (int o = 32; o; o >>= 1) bc += __shfl_xor(bc, o);
    if (c == 0) biasc[rr] = bc;
  }
  __syncthreads();
  for (int i = tid; i < 784; i += 256) {
    int r = i / 196, k = i - r * 196;
    const float4* b4 = (const float4*)(arp + ((size_t)(sb + r) * 196 + k) * cC);
    const float* fv = featc + r * 64;
    float acc = 0.f;
    #pragma unroll
    for (int c4 = 0; c4 < 16; c4++) {
      float4 v = b4[c4];
      acc += v.x * fv[c4 * 4 + 0] + v.y * fv[c4 * 4 + 1] +
             v.z * fv[c4 * 4 + 2] + v.w * fv[c4 * 4 + 3];
    }
    fc[i] = acc + biasc[r];
  }
  __syncthreads();
  int j = tid & 127, half = tid >> 7;
  float h0 = 0.f, h1 = 0.f, h2v = 0.f, h3 = 0.f;
  int k0 = half * 98;
  for (int k = k0; k < k0 + 98; k++) {
    float wv = w1[(size_t)k * 128 + j];
    h0 += fc[0 * 196 + k] * wv; h1 += fc[1 * 196 + k] * wv;
    h2v += fc[2 * 196 + k] * wv; h3 += fc[3 * 196 + k] * wv;
  }
  hp[(half * 4 + 0) * 128 + j] = h0; hp[(half * 4 + 1) * 128 + j] = h1;
  hp[(half * 4 + 2) * 128 + j] = h2v; hp[(half * 4 + 3) * 128 + j] = h3;
  __syncthreads();
  if (half == 0) {
    const float* Wxy = w1 + (size_t)3198 * 128;
    #pragma unroll
    for (int r = 0; r < 4; r++) {
      int s = sb + r;
      float v = hp[r * 128 + j] + hp[(4 + r) * 128 + j] + b1[j] +
                ffw[s * 128 + j] + xx * Wxy[j] + yy * Wxy[128 + j];
      hl[r * 128 + j] = fmaxf(v, 0.f);
    }
  }
  __syncthreads();
  if (tid < 8) {
    int r = tid >> 1, d = tid & 1;
    float acc = b2[d];
    for (int k = 0; k < 128; k++) acc += hl[r * 128 + k] * w2[k * 2 + d];
    int s = sb + r;
    float cc = pts[n * 2 + d] * 0.125f + acc;
    out[((size_t)s * cN + n) * 2 + d] = cc * 8.0f;   // preds[0]
    cof[((size_t)s * cN + n) * 2 + d] = cc * 4.0f;   // fine coords init
    if (s == 0) xys[n * 2 + d] = cc * 4.0f;
  }
}

// ---------------------------------------------------------------------------
// k_iter: fused corr + window-sample + fine MLP + coords update.
// TWO rows per block (rows w and w+512, i.e. (s,n) and (s+8,n)): the 294-deep
// GEMV reads LWc ONCE for both rows (halves L2 traffic vs 1-row blocks).
// grid = 512 (XCD-swizzled), block = 256.
// ---------------------------------------------------------------------------
__global__ __launch_bounds__(256) void k_iter(const _Float16* __restrict__ p0, const _Float16* __restrict__ p1,
                                              const _Float16* __restrict__ p2, const _Float16* __restrict__ p3,
                                              const float* __restrict__ stats,
                                              const h2* __restrict__ LWc2, const float* __restrict__ b1e,
                                              const float* __restrict__ ffw, const float* __restrict__ w1t,
                                              const float* __restrict__ w2, const float* __restrict__ b2,
                                              const float* __restrict__ cof_cur, float* __restrict__ cof_nxt,
                                              const float* __restrict__ xys, float* __restrict__ out) {
  int bid = blockIdx.x;
  int w = (bid & 7) * 64 + (bid >> 3);   // XCD swizzle over 512
  int n = w & 63;
  int srow[2] = {w >> 6, (w >> 6) + 8};
  __shared__ _Float16 feat2h[2][3][64];
  __shared__ float biasS[2][3];
  __shared__ _Float16 fcL16[2][588];
  __shared__ float hp[2][2][128];
  __shared__ float hl[2][128];
  int tid = threadIdx.x;

  // ---- phase A: normalized feature vectors for both rows (6 units) ----
  {
    int c = tid & 63, wv = tid >> 6;
    #pragma unroll
    for (int pass = 0; pass < 2; pass++) {
      int u = wv + pass * 4;
      if (u < 6) {
        int r = u >> 1 >= 3 ? 1 : u / 3;  // u in [0,6): r = u/3
        r = u / 3;
        int t = u - r * 3;
        int s = srow[r];
        float sS = stats[(s * 64 + c) * 2 + 0], qS = stats[(s * 64 + c) * 2 + 1];
        float meanS = sS / 12000.f, varS = qS / 12000.f - meanS * meanS;
        float rstdS = rsqrtf(varS + 1e-5f);
        int ssrc = (t == 0) ? 0 : max(s - 2 * t, 0);
        float fx, fy;
        if (t == 0) { fx = xys[n * 2 + 0]; fy = xys[n * 2 + 1]; }
        else {
          fx = cof_cur[((size_t)ssrc * cN + n) * 2 + 0];
          fy = cof_cur[((size_t)ssrc * cN + n) * 2 + 1];
        }
        float s2 = stats[(ssrc * 64 + c) * 2 + 0], q2 = stats[(ssrc * 64 + c) * 2 + 1];
        float m2 = s2 / 12000.f, v2 = q2 / 12000.f - m2 * m2;
        float r2 = rsqrtf(v2 + 1e-5f);
        float ws;
        float raw = bilin_raw_h(p0 + (size_t)ssrc * cHF * cWF * cC, cHF, cWF, fx, fy, c, ws);
        float featn = (raw - m2 * ws) * r2;
        feat2h[r][t][c] = (_Float16)(featn * rstdS * 0.125f);   // 1/sqrt(64) folded
        float bc = featn * (-meanS * rstdS) * 0.125f;
        #pragma unroll
        for (int o = 32; o; o >>= 1) bc += __shfl_xor(bc, o);
        if (c == 0) biasS[r][t] = bc;
      }
    }
  }
  __syncthreads();

  // ---- gather + 3 dot2-dots per 8x8 grid point, per row ----
  {
    int l = tid >> 6, lane = tid & 63;
    const _Float16* Ls[4] = {p0, p1, p2, p3};
    const int Hs[4] = {cHF, 50, 25, 12}, Ws[4] = {cWF, 60, 30, 15};
    int dxi = lane & 7, dyi = lane >> 3;
    int dy7 = lane / 7, dx7 = lane - dy7 * 7;
    int bb = (lane < 49) ? (dy7 * 8 + dx7) : 0;
    #pragma unroll
    for (int r = 0; r < 2; r++) {
      int s = srow[r];
      const h2* fh0 = (const h2*)feat2h[r][0];
      const h2* fh1 = (const h2*)feat2h[r][1];
      const h2* fh2 = (const h2*)feat2h[r][2];
      float cx = cof_cur[((size_t)s * cN + n) * 2 + 0];
      float cy = cof_cur[((size_t)s * cN + n) * 2 + 1];
      float sc = 1.0f / (float)(1 << l);
      float x = fminf(fmaxf(cx * sc, -2.0e6f), 2.0e6f);
      float y = fminf(fmaxf(cy * sc, -2.0e6f), 2.0e6f);
      float x0f = floorf(x), y0f = floorf(y);
      float wx = x - x0f, wy = y - y0f;
      int ix = (int)x0f + dxi - 3, iy = (int)y0f + dyi - 3;
      int Hl = Hs[l], Wl = Ws[l];
      float d[3] = {0.f, 0.f, 0.f};
      if (ix >= 0 && ix < Wl && iy >= 0 && iy < Hl) {
        const _Float16* row = Ls[l] + (((size_t)s * Hl + iy) * Wl + ix) * cC;
        float a0 = 0.f, a1 = 0.f, a2 = 0.f;
        #pragma unroll
        for (int c8 = 0; c8 < 8; c8++) {
          half8 v = *(const half8*)(row + c8 * 8);
          #pragma unroll
          for (int e2 = 0; e2 < 4; e2++) {
            h2 pv = {v[e2 * 2], v[e2 * 2 + 1]};
            a0 = __builtin_amdgcn_fdot2(pv, fh0[c8 * 4 + e2], a0, false);
            a1 = __builtin_amdgcn_fdot2(pv, fh1[c8 * 4 + e2], a1, false);
            a2 = __builtin_amdgcn_fdot2(pv, fh2[c8 * 4 + e2], a2, false);
          }
        }
        d[0] = a0 + biasS[r][0]; d[1] = a1 + biasS[r][1]; d[2] = a2 + biasS[r][2];
      }
      float w00 = (1.f - wy) * (1.f - wx), w01 = (1.f - wy) * wx;
      float w10 = wy * (1.f - wx), w11 = wy * wx;
      #pragma unroll
      for (int t = 0; t < 3; t++) {
        float d00 = __shfl(d[t], bb, 64);
        float d01 = __shfl(d[t], bb + 1, 64);
        float d10 = __shfl(d[t], bb + 8, 64);
        float d11 = __shfl(d[t], bb + 9, 64);
        if (lane < 49)
          fcL16[r][t * 196 + l * 49 + lane] =
              (_Float16)(w00 * d00 + w01 * d01 + w10 * d10 + w11 * d11);
      }
    }
  }
  __syncthreads();

  // ---- phase B: shared-LWc GEMV for both rows + coords update ----
  int j = tid & 127, half = tid >> 7;
  {
    const h2* f0 = (const h2*)fcL16[0];
    const h2* f1 = (const h2*)fcL16[1];
    float h0 = 0.f, h1 = 0.f;
    int kk0 = half * 147;
    const h2* Lw = LWc2 + (size_t)kk0 * 128 + j;
    #pragma unroll 4
    for (int kk = 0; kk < 147; kk++) {
      h2 wv = Lw[(size_t)kk * 128];
      h0 = __builtin_amdgcn_fdot2(f0[kk0 + kk], wv, h0, false);
      h1 = __builtin_amdgcn_fdot2(f1[kk0 + kk], wv, h1, false);
    }
    hp[half][0][j] = h0; hp[half][1][j] = h1;
  }
  __syncthreads();
  {
    int r = half;          // each half finishes one row
    int s = srow[r];
    const float* Wfl = w1t + (size_t)392 * 128;
    const float* Wxy = w1t + (size_t)3394 * 128;
    float xx = xys[n * 2 + 0], yy = xys[n * 2 + 1];
    int sA = min(s + 1, 15), sB = (s == 15) ? 14 : s;
    float flx = cof_cur[(sA * cN + n) * 2 + 0] - cof_cur[(sB * cN + n) * 2 + 0];
    float fly = cof_cur[(sA * cN + n) * 2 + 1] - cof_cur[(sB * cN + n) * 2 + 1];
    float v = hp[0][r][j] + hp[1][r][j] + b1e[j] + ffw[s * 128 + j] +
              flx * Wfl[j] + fly * Wfl[128 + j] + xx * Wxy[j] + yy * Wxy[128 + j];
    hl[r][j] = fmaxf(v, 0.f);
  }
  __syncthreads();
  if (tid < 4) {
    int r = tid >> 1, d = tid & 1;
    int s = srow[r];
    float acc = b2[d];
    for (int k = 0; k < 128; k++) acc += hl[r][k] * w2[k * 2 + d];
    float cc = cof_cur[((size_t)s * cN + n) * 2 + d] + acc;
    cof_nxt[((size_t)s * cN + n) * 2 + d] = cc;
    out[((size_t)s * cN + n) * 2 + d] = cc * 2.0f;
  }
}

// ---------------------------------------------------------------------------
extern "C" void kernel_launch(void* const* d_in, const int* in_sizes, int n_in,
                              void* d_out, int out_size, void* d_ws, size_t ws_size,
                              hipStream_t stream) {
  (void)in_sizes; (void)n_in; (void)out_size; (void)ws_size;
  const float* rgbs = (const float*)d_in[0];
  const float* pts  = (const float*)d_in[1];
  const float* fnw  = (const float*)d_in[2];
  const float* fnfw = (const float*)d_in[3];
  const float* lw   = (const float*)d_in[4];
  const float* lb   = (const float*)d_in[5];
  const float* w1s  = (const float*)d_in[6];
  const float* b1s  = (const float*)d_in[7];
  const float* w2s  = (const float*)d_in[8];
  const float* b2s  = (const float*)d_in[9];
  const float* w1t  = (const float*)d_in[10];
  const float* b1t  = (const float*)d_in[11];
  const float* w2t  = (const float*)d_in[12];
  const float* b2t  = (const float*)d_in[13];
  float* out = (float*)d_out;

  float* p = (float*)d_ws;
  auto alloc = [&](size_t nf) { float* r = p; p += nf; return r; };
  float* part  = alloc((size_t)2 * cS * cNCH * 128);
  float* ffw_s = alloc(cS * 128);
  float* ffw_t = alloc(cS * 128);
  h2* LWc2     = (h2*)alloc((size_t)588 * 128 / 2);
  float* b1te  = alloc(128);
  _Float16* fmc = (_Float16*)alloc((size_t)cS * 750 * cC / 2);
  float* partc = alloc((size_t)cS * 25 * cC * 2);
  float* statc = alloc(cS * cC * 2);
  float* arp   = alloc((size_t)cS * 196 * cC);
  float* partf = alloc((size_t)cS * cHF * cC * 2);
  float* stats = alloc(cS * cC * 2);
  _Float16* fmf = (_Float16*)alloc((size_t)cS * cHF * cWF * cC / 2);
  _Float16* pf1 = (_Float16*)alloc((size_t)cS * 50 * 60 * cC / 2);
  _Float16* pf2 = (_Float16*)alloc((size_t)cS * 25 * 30 * cC / 2);
  _Float16* pf3 = (_Float16*)alloc((size_t)cS * 12 * 15 * cC / 2);
  float* xys0  = alloc(cN * 2);
  float* cofA  = alloc((size_t)cS * cN * 2);
  float* cofB  = alloc((size_t)cS * cN * 2);

  // 1) independent front work
  k_front<<<NB_FFP + NB_CONVC + NB_CONVF, 256, 0, stream>>>(
      rgbs, w1s, w1t, fnw, fnfw, part, fmc, partc, fmf, partf);
  // 2) reductions + precomputes + fine pyramid
  k_mid<<<347, 256, 0, stream>>>(part, ffw_s, ffw_t, lw, lb, w1t, b1t, LWc2, b1te,
                                 partf, stats, partc, statc, fmc, arp,
                                 fmf, pf1, pf2, pf3);
  // 3) coarse MLP
  k_mix<<<256, 256, 0, stream>>>(arp, fmc, statc, w1s, b1s, ffw_s, w2s, b2s, pts,
                                 cofA, xys0, out);
  // 4-7) fused fine iterations (2 rows per block)
  float* cbuf[2] = {cofA, cofB};
  for (int it = 0; it < cITERS; it++) {
    float* cur = cbuf[it & 1];
    float* nxt = cbuf[(it & 1) ^ 1];
    k_iter<<<512, 256, 0, stream>>>(fmf, pf1, pf2, pf3, stats, LWc2, b1te, ffw_t,
                                    w1t, w2t, b2t, cur, nxt, xys0,
                                    out + (size_t)(it + 1) * cS * cN * 2);
  }
}

// Round 11
// 172.503 us; speedup vs baseline: 1.0663x; 1.0663x over previous
//
#include <hip/hip_runtime.h>

// ---- problem constants (from reference setup_inputs) ----
constexpr int cS = 16, cN = 64, cH = 200, cW = 240;
constexpr int cHC = 25, cWC = 30;          // coarse fmap (stride 8)
constexpr int cHF = 100, cWF = 120;        // fine fmap (stride 2)
constexpr int cC = 64;                     // LAT
constexpr int cITERS = 4;                  // setup_inputs fixed
constexpr int cNCH = 50, cCHUNK = 60;      // ffw split

typedef _Float16 half8 __attribute__((ext_vector_type(8)));

// NOTE (round 7 lesson): hipLaunchCooperativeKernel fails under this harness's
// graph capture (output never written). Stay with normal stream launches.
// NOTE (round 9/10 lessons): k_iter is gather-LATENCY-bound — 1024 blocks
// (1 row/block) beats 512 blocks (2 rows/block) despite 2x LWc L2 traffic;
// fp16 dot2 conversions are neutral. This is the round-8 best (172.3 us).

// ---------------------------------------------------------------------------
// helpers
// ---------------------------------------------------------------------------
__device__ __forceinline__ float bilin_hwc(const float* __restrict__ fm, int Hh, int Ww,
                                           float x, float y, int c) {
  x = fminf(fmaxf(x, -2.0e6f), 2.0e6f);
  y = fminf(fmaxf(y, -2.0e6f), 2.0e6f);
  float x0f = floorf(x), y0f = floorf(y);
  int ix = (int)x0f, iy = (int)y0f;
  float wx = x - x0f, wy = y - y0f;
  float acc = 0.f;
  bool vx0 = (ix >= 0) && (ix < Ww), vx1 = (ix + 1 >= 0) && (ix + 1 < Ww);
  bool vy0 = (iy >= 0) && (iy < Hh), vy1 = (iy + 1 >= 0) && (iy + 1 < Hh);
  if (vy0 && vx0) acc += fm[(iy * Ww + ix) * cC + c] * (1.f - wy) * (1.f - wx);
  if (vy0 && vx1) acc += fm[(iy * Ww + ix + 1) * cC + c] * (1.f - wy) * wx;
  if (vy1 && vx0) acc += fm[((iy + 1) * Ww + ix) * cC + c] * wy * (1.f - wx);
  if (vy1 && vx1) acc += fm[((iy + 1) * Ww + ix + 1) * cC + c] * wy * wx;
  return acc;
}

// raw fp16 bilinear gather; returns in-bounds tap-weight sum (affine folding:
// featn = rstd*(raw - mean*wsum), zero-padding-correct).
__device__ __forceinline__ float bilin_raw_h(const _Float16* __restrict__ fm, int Hh, int Ww,
                                             float x, float y, int c, float& wsum) {
  x = fminf(fmaxf(x, -2.0e6f), 2.0e6f);
  y = fminf(fmaxf(y, -2.0e6f), 2.0e6f);
  float x0f = floorf(x), y0f = floorf(y);
  int ix = (int)x0f, iy = (int)y0f;
  float wx = x - x0f, wy = y - y0f;
  float acc = 0.f; wsum = 0.f;
  bool vx0 = (ix >= 0) && (ix < Ww), vx1 = (ix + 1 >= 0) && (ix + 1 < Ww);
  bool vy0 = (iy >= 0) && (iy < Hh), vy1 = (iy + 1 >= 0) && (iy + 1 < Hh);
  float w00 = (1.f - wy) * (1.f - wx), w01 = (1.f - wy) * wx;
  float w10 = wy * (1.f - wx), w11 = wy * wx;
  if (vy0 && vx0) { acc += (float)fm[(iy * Ww + ix) * cC + c] * w00; wsum += w00; }
  if (vy0 && vx1) { acc += (float)fm[(iy * Ww + ix + 1) * cC + c] * w01; wsum += w01; }
  if (vy1 && vx0) { acc += (float)fm[((iy + 1) * Ww + ix) * cC + c] * w10; wsum += w10; }
  if (vy1 && vx1) { acc += (float)fm[((iy + 1) * Ww + ix + 1) * cC + c] * w11; wsum += w11; }
  return acc;
}

// ---------------------------------------------------------------------------
// k_front: role-partitioned. [0,800) ffp; [800,1824) convc; [1824,3424) convf.
// ---------------------------------------------------------------------------
constexpr int NB_FFP = 800, NB_CONVC = 1024, NB_CONVF = 1600;

__global__ __launch_bounds__(256) void k_front(const float* __restrict__ rgbs,
                                               const float* __restrict__ w1s,
                                               const float* __restrict__ w1t,
                                               const float* __restrict__ fnw,
                                               const float* __restrict__ fnfw,
                                               float* __restrict__ part,
                                               float* __restrict__ fmc,
                                               _Float16* __restrict__ fmf,
                                               float* __restrict__ partf) {
  __shared__ float smem[512];
  int bid = blockIdx.x, tid = threadIdx.x;
  const float a = 2.0f / 255.0f;

  if (bid < NB_FFP) {
    int s = bid / cNCH, ch = bid % cNCH;
    if (tid < cCHUNK) {
      const float* cur = rgbs + (size_t)s * cH * cW;
      const float* prev = rgbs + (size_t)(s - 1) * cH * cW;
      const float* last = rgbs + (size_t)15 * cH * cW;
      int y = 4 * ch + 1, x = 4 * tid + 1;
      float v = 0.f;
      #pragma unroll
      for (int dy = 0; dy < 2; dy++)
        #pragma unroll
        for (int dx = 0; dx < 2; dx++) {
          int id = (y + dy) * cW + (x + dx);
          float pv = (s == 0) ? (a * last[id] - 1.0f) : (a * (cur[id] - prev[id]));
          v += pv;
        }
      smem[tid] = 0.25f * v;
    }
    __syncthreads();
    int t = tid >> 7, j = tid & 127;
    const float* w = (t == 0) ? (w1s + (size_t)198 * 128) : (w1t + (size_t)394 * 128);
    const float* wr = w + (size_t)ch * cCHUNK * 128 + j;
    float acc = 0.f;
    #pragma unroll 4
    for (int i = 0; i < cCHUNK; i++) acc += smem[i] * wr[(size_t)i * 128];
    part[(((size_t)t * cS + s) * cNCH + ch) * 128 + j] = acc;

  } else if (bid < NB_FFP + NB_CONVC) {
    int idx = bid - NB_FFP;
    int q = idx >> 6, c = idx & 63;
    float* wl = smem;
    float* red = smem + 64;
    if (tid < 64) wl[tid] = fnw[c * 64 + tid];
    __syncthreads();
    const float* img = rgbs + (size_t)q * cH * cW;
    float vals[3];
    float sum = 0.f, ss = 0.f;
    #pragma unroll
    for (int i = 0; i < 3; i++) {
      int pos = tid + i * 256;
      float v = 0.f;
      if (pos < 750) {
        int y = pos / cWC, x = pos % cWC;
        const float* base = img + (y * 8) * cW + x * 8;
        float acc = 0.f, wsum = 0.f;
        for (int ky = 0; ky < 8; ky++)
          #pragma unroll
          for (int kx = 0; kx < 8; kx++) {
            float wv = wl[ky * 8 + kx];
            acc += wv * base[ky * cW + kx];
            wsum += wv;
          }
        v = a * acc - wsum;
        sum += v; ss += v * v;
      }
      vals[i] = v;
    }
    red[tid] = sum; __syncthreads();
    for (int st = 128; st > 0; st >>= 1) { if (tid < st) red[tid] += red[tid + st]; __syncthreads(); }
    float tsum = red[0]; __syncthreads();
    red[tid] = ss; __syncthreads();
    for (int st = 128; st > 0; st >>= 1) { if (tid < st) red[tid] += red[tid + st]; __syncthreads(); }
    float tss = red[0];
    float mean = tsum / 750.0f;
    float var = tss / 750.0f - mean * mean;
    float rstd = rsqrtf(var + 1e-5f);
    #pragma unroll
    for (int i = 0; i < 3; i++) {
      int pos = tid + i * 256;
      if (pos < 750) fmc[((size_t)q * 750 + pos) * cC + c] = (vals[i] - mean) * rstd;
    }

  } else {
    int idx = bid - NB_FFP - NB_CONVC;
    int q = idx / cHF, y = idx % cHF;
    int lane = tid & 63, wv = tid >> 6;
    float w0 = fnfw[lane * 4 + 0], w1 = fnfw[lane * 4 + 1];
    float w2 = fnfw[lane * 4 + 2], w3 = fnfw[lane * 4 + 3];
    float wsum = w0 + w1 + w2 + w3;
    const float* img = rgbs + (size_t)q * cH * cW;
    float sum = 0.f, ss = 0.f;
    for (int x = wv; x < cWF; x += 4) {
      const float* b = img + (2 * y) * cW + 2 * x;
      float v = a * (w0 * b[0] + w1 * b[1] + w2 * b[cW] + w3 * b[cW + 1]) - wsum;
      fmf[(((size_t)q * cHF + y) * cWF + x) * cC + lane] = (_Float16)v;
      sum += v; ss += v * v;
    }
    float* red = smem;
    red[(0 * 4 + wv) * 64 + lane] = sum;
    red[(1 * 4 + wv) * 64 + lane] = ss;
    __syncthreads();
    if (wv == 0) {
      float s4 = red[0 * 64 + lane] + red[1 * 64 + lane] + red[2 * 64 + lane] + red[3 * 64 + lane];
      float q4 = red[(4 + 0) * 64 + lane] + red[(4 + 1) * 64 + lane] +
                 red[(4 + 2) * 64 + lane] + red[(4 + 3) * 64 + lane];
      size_t o = ((size_t)q * cHF + y) * 64 + lane;
      partf[o * 2 + 0] = s4;
      partf[o * 2 + 1] = q4;
    }
  }
}

// ---------------------------------------------------------------------------
// k_mid: [0,16) ffw_red; [16,91) LWc + b1te; [91,107) stats reduce;
// [107,123) coarse pyramid + arp.
// ---------------------------------------------------------------------------
__global__ __launch_bounds__(256) void k_mid(const float* __restrict__ part,
                                             float* __restrict__ ffw_s, float* __restrict__ ffw_t,
                                             const float* __restrict__ lw, const float* __restrict__ lb,
                                             const float* __restrict__ w1t, const float* __restrict__ b1t,
                                             _Float16* __restrict__ LWc, float* __restrict__ b1te,
                                             const float* __restrict__ partf, float* __restrict__ stats,
                                             const float* __restrict__ fmc, float* __restrict__ arp) {
  __shared__ float smem[14784];
  int bid = blockIdx.x, tid = threadIdx.x;

  if (bid < 16) {
    int s = bid, t = tid >> 7, j = tid & 127;
    const float* p = part + (((size_t)t * cS + s) * cNCH) * 128 + j;
    float acc = 0.f;
    for (int c = 0; c < cNCH; c++) acc += p[(size_t)c * 128];
    ((t == 0) ? ffw_s : ffw_t)[s * 128 + j] = acc;

  } else if (bid < 91) {
    int b2 = bid - 16, g = tid >> 7, j = tid & 127;
    if (b2 < 74) {
      int k0 = b2 * 8 + g * 4;
      if (k0 < 588) {
        const float* l0 = lw + (size_t)(k0 + 0) * 392;
        const float* l1 = lw + (size_t)(k0 + 1) * 392;
        const float* l2 = lw + (size_t)(k0 + 2) * 392;
        const float* l3 = lw + (size_t)(k0 + 3) * 392;
        float a0 = 0.f, a1 = 0.f, a2 = 0.f, a3 = 0.f;
        for (int m = 0; m < 392; m++) {
          float wv = w1t[(size_t)m * 128 + j];
          a0 += l0[m] * wv; a1 += l1[m] * wv; a2 += l2[m] * wv; a3 += l3[m] * wv;
        }
        LWc[(size_t)(k0 + 0) * 128 + j] = (_Float16)a0;
        LWc[(size_t)(k0 + 1) * 128 + j] = (_Float16)a1;
        LWc[(size_t)(k0 + 2) * 128 + j] = (_Float16)a2;
        LWc[(size_t)(k0 + 3) * 128 + j] = (_Float16)a3;
      }
    } else if (g == 0) {
      float acc = b1t[j];
      for (int m = 0; m < 392; m++) acc += lb[m] * w1t[(size_t)m * 128 + j];
      b1te[j] = acc;
    }

  } else if (bid < 107) {
    int q = bid - 91, c = tid & 63, g = tid >> 6;
    float s0 = 0.f, s1 = 0.f;
    for (int yy = 0; yy < 25; yy++) {
      size_t o = ((size_t)q * cHF + g * 25 + yy) * 64 + c;
      s0 += partf[o * 2 + 0];
      s1 += partf[o * 2 + 1];
    }
    smem[g * 64 + c] = s0;
    smem[256 + g * 64 + c] = s1;
    __syncthreads();
    if (g == 0) {
      stats[(q * 64 + c) * 2 + 0] = smem[c] + smem[64 + c] + smem[128 + c] + smem[192 + c];
      stats[(q * 64 + c) * 2 + 1] = smem[256 + c] + smem[320 + c] + smem[384 + c] + smem[448 + c];
    }

  } else {
    int q = bid - 107;
    float* pc1 = smem;            // 12*15*64
    float* pc2 = smem + 11520;    // 6*7*64
    float* pc3 = smem + 14208;    // 3*3*64
    const float* L0 = fmc + (size_t)q * 750 * cC;
    for (int i = tid; i < 12 * 15 * 64; i += 256) {
      int c = i & 63, pos = i >> 6, oy = pos / 15, ox = pos % 15;
      const float* b = L0 + ((2 * oy) * 30 + 2 * ox) * cC + c;
      pc1[i] = 0.25f * (b[0] + b[cC] + b[30 * cC] + b[30 * cC + cC]);
    }
    __syncthreads();
    for (int i = tid; i < 6 * 7 * 64; i += 256) {
      int c = i & 63, pos = i >> 6, oy = pos / 7, ox = pos % 7;
      const float* b = pc1 + ((2 * oy) * 15 + 2 * ox) * cC + c;
      pc2[i] = 0.25f * (b[0] + b[cC] + b[15 * cC] + b[15 * cC + cC]);
    }
    __syncthreads();
    for (int i = tid; i < 3 * 3 * 64; i += 256) {
      int c = i & 63, pos = i >> 6, oy = pos / 3, ox = pos % 3;
      const float* b = pc2 + ((2 * oy) * 7 + 2 * ox) * cC + c;
      pc3[i] = 0.25f * (b[0] + b[cC] + b[7 * cC] + b[7 * cC + cC]);
    }
    __syncthreads();
    const int Hs[4] = {25, 12, 6, 3}, Ws[4] = {30, 15, 7, 3};
    for (int i = tid; i < 196 * 64; i += 256) {
      int c = i & 63, pos = i >> 6, o = pos / 14, p = pos % 14;
      float acc = 0.f;
      #pragma unroll
      for (int l = 0; l < 4; l++) {
        float yy = (float)(o * (Hs[l] - 1)) / 13.0f;
        float xx = (float)(p * (Ws[l] - 1)) / 13.0f;
        int y0 = (int)floorf(yy); int y1 = min(y0 + 1, Hs[l] - 1); float wy = yy - (float)y0;
        int x0 = (int)floorf(xx); int x1 = min(x0 + 1, Ws[l] - 1); float wx = xx - (float)x0;
        const float* L = (l == 0) ? L0 : ((l == 1) ? pc1 : ((l == 2) ? pc2 : pc3));
        float v00 = L[(y0 * Ws[l] + x0) * cC + c], v01 = L[(y0 * Ws[l] + x1) * cC + c];
        float v10 = L[(y1 * Ws[l] + x0) * cC + c], v11 = L[(y1 * Ws[l] + x1) * cC + c];
        acc += (v00 * (1.f - wy) + v10 * wy) * (1.f - wx) + (v01 * (1.f - wy) + v11 * wy) * wx;
      }
      arp[((size_t)q * 196 + pos) * cC + c] = acc * 0.25f * 0.125f;
    }
  }
}

// ---------------------------------------------------------------------------
// k_mix: [0,256) coarse MLP (4 rows per block, 256 threads, K-split GEMV);
//        [256,464) fine pyramid. Independent roles (MLP needs k_mid's arp/ffw;
//        pyramid needs k_front's fmf) -> one dispatch.
// ---------------------------------------------------------------------------
__global__ __launch_bounds__(256) void k_mix(const float* __restrict__ arp, const float* __restrict__ fmc,
                                             const float* __restrict__ w1, const float* __restrict__ b1,
                                             const float* __restrict__ ffw, const float* __restrict__ w2,
                                             const float* __restrict__ b2, const float* __restrict__ pts,
                                             float* __restrict__ cof, float* __restrict__ xys,
                                             float* __restrict__ out,
                                             const _Float16* __restrict__ fmf,
                                             _Float16* __restrict__ pf1, _Float16* __restrict__ pf2,
                                             _Float16* __restrict__ pf3) {
  __shared__ __align__(16) unsigned char smemraw[38400];
  int bid = blockIdx.x, tid = threadIdx.x;

  if (bid < 256) {
    // ---- coarse MLP; flow term is exactly zero (broadcast pre-update) ----
    int n = bid >> 2, sb = (bid & 3) * 4;
    float* fc = (float*)smemraw;   // [784]
    float* f0l = fc + 784;         // [64]
    float* hp = f0l + 64;          // [2][4][128]
    float* hl = hp + 1024;         // [4][128]
    float xx = pts[n * 2 + 0] * 0.125f, yy = pts[n * 2 + 1] * 0.125f;
    if (tid < 64) f0l[tid] = bilin_hwc(fmc, cHC, cWC, xx, yy, tid);
    __syncthreads();
    for (int i = tid; i < 784; i += 256) {
      int r = i / 196, k = i - r * 196;
      const float4* b4 = (const float4*)(arp + ((size_t)(sb + r) * 196 + k) * cC);
      float acc = 0.f;
      #pragma unroll
      for (int c4 = 0; c4 < 16; c4++) {
        float4 v = b4[c4];
        acc += v.x * f0l[c4 * 4 + 0] + v.y * f0l[c4 * 4 + 1] +
               v.z * f0l[c4 * 4 + 2] + v.w * f0l[c4 * 4 + 3];
      }
      fc[i] = acc;
    }
    __syncthreads();
    int j = tid & 127, half = tid >> 7;
    float h0 = 0.f, h1 = 0.f, h2 = 0.f, h3 = 0.f;
    int k0 = half * 98;
    for (int k = k0; k < k0 + 98; k++) {
      float wv = w1[(size_t)k * 128 + j];
      h0 += fc[0 * 196 + k] * wv; h1 += fc[1 * 196 + k] * wv;
      h2 += fc[2 * 196 + k] * wv; h3 += fc[3 * 196 + k] * wv;
    }
    hp[(half * 4 + 0) * 128 + j] = h0; hp[(half * 4 + 1) * 128 + j] = h1;
    hp[(half * 4 + 2) * 128 + j] = h2; hp[(half * 4 + 3) * 128 + j] = h3;
    __syncthreads();
    if (half == 0) {
      const float* Wxy = w1 + (size_t)3198 * 128;
      #pragma unroll
      for (int r = 0; r < 4; r++) {
        int s = sb + r;
        float v = hp[r * 128 + j] + hp[(4 + r) * 128 + j] + b1[j] +
                  ffw[s * 128 + j] + xx * Wxy[j] + yy * Wxy[128 + j];
        hl[r * 128 + j] = fmaxf(v, 0.f);
      }
    }
    __syncthreads();
    if (tid < 8) {
      int r = tid >> 1, d = tid & 1;
      float acc = b2[d];
      for (int k = 0; k < 128; k++) acc += hl[r * 128 + k] * w2[k * 2 + d];
      int s = sb + r;
      float cc = pts[n * 2 + d] * 0.125f + acc;
      out[((size_t)s * cN + n) * 2 + d] = cc * 8.0f;   // preds[0]
      cof[((size_t)s * cN + n) * 2 + d] = cc * 4.0f;   // fine coords init
      if (s == 0) xys[n * 2 + d] = cc * 4.0f;
    }

  } else {
    // ---- fine pyramid ----
    int u = bid - 256;
    int q = u / 13, b = u % 13;
    _Float16* l1 = (_Float16*)smemraw;  // [4*60*64]
    _Float16* l2 = l1 + 15360;          // [2*30*64]
    int nr1 = (b == 12) ? 2 : 4;
    const _Float16* F = fmf + (size_t)q * cHF * cWF * cC;
    for (int i = tid; i < nr1 * 60 * 64; i += 256) {
      int c = i & 63, pos = i >> 6, rl = pos / 60, ox = pos % 60;
      int r1 = 4 * b + rl;
      const _Float16* p = F + ((size_t)(2 * r1) * cWF + 2 * ox) * cC + c;
      float v = 0.25f * ((float)p[0] + (float)p[cC] + (float)p[cWF * cC] + (float)p[cWF * cC + cC]);
      _Float16 h = (_Float16)v;
      l1[i] = h;
      pf1[(((size_t)q * 50 + r1) * 60 + ox) * cC + c] = h;
    }
    __syncthreads();
    int nr2 = (b == 12) ? 1 : 2;
    for (int i = tid; i < nr2 * 30 * 64; i += 256) {
      int c = i & 63, pos = i >> 6, rl = pos / 30, ox = pos % 30;
      const _Float16* p = l1 + ((2 * rl) * 60 + 2 * ox) * 64 + c;
      float v = 0.25f * ((float)p[0] + (float)p[64] + (float)p[60 * 64] + (float)p[60 * 64 + 64]);
      _Float16 h = (_Float16)v;
      l2[i] = h;
      pf2[(((size_t)q * 25 + 2 * b + rl) * 30 + ox) * cC + c] = h;
    }
    __syncthreads();
    if (b < 12) {
      for (int i = tid; i < 15 * 64; i += 256) {
        int c = i & 63, ox = i >> 6;
        const _Float16* p = l2 + (2 * ox) * 64 + c;
        float v = 0.25f * ((float)p[0] + (float)p[64] + (float)p[30 * 64] + (float)p[30 * 64 + 64]);
        pf3[(((size_t)q * 12 + b) * 15 + ox) * cC + c] = (_Float16)v;
      }
    }
  }
}

// ---------------------------------------------------------------------------
// k_iter: fused corr + window-sample + fine MLP + coords update.
// grid = 1024 (XCD-swizzled), block = 256. feat2[0] recomputed in-block from
// xys0 (frame-0 gather) — no precomputed f0 buffer needed.
// ---------------------------------------------------------------------------
__global__ __launch_bounds__(256) void k_iter(const _Float16* __restrict__ p0, const _Float16* __restrict__ p1,
                                              const _Float16* __restrict__ p2, const _Float16* __restrict__ p3,
                                              const float* __restrict__ stats,
                                              const _Float16* __restrict__ LWc, const float* __restrict__ b1e,
                                              const float* __restrict__ ffw, const float* __restrict__ w1t,
                                              const float* __restrict__ w2, const float* __restrict__ b2,
                                              const float* __restrict__ cof_cur, float* __restrict__ cof_nxt,
                                              const float* __restrict__ xys, float* __restrict__ out) {
  int bid = blockIdx.x;
  int w = (bid & 7) * 128 + (bid >> 3);
  int s = w >> 6, n = w & 63;
  __shared__ float feat2[3][64];
  __shared__ float biasS[3];
  __shared__ float fcL[588];
  __shared__ float hp[2][128];
  __shared__ float hl[128];
  int tid = threadIdx.x;

  // ---- phase A: normalized feature vectors (norm affine folded) ----
  {
    int t = tid >> 6, c = tid & 63;
    if (t < 3) {
      float sS = stats[(s * 64 + c) * 2 + 0], qS = stats[(s * 64 + c) * 2 + 1];
      float meanS = sS / 12000.f, varS = qS / 12000.f - meanS * meanS;
      float rstdS = rsqrtf(varS + 1e-5f);
      int ssrc = (t == 0) ? 0 : max(s - 2 * t, 0);
      float fx, fy;
      if (t == 0) { fx = xys[n * 2 + 0]; fy = xys[n * 2 + 1]; }
      else {
        fx = cof_cur[((size_t)ssrc * cN + n) * 2 + 0];
        fy = cof_cur[((size_t)ssrc * cN + n) * 2 + 1];
      }
      float s2 = stats[(ssrc * 64 + c) * 2 + 0], q2 = stats[(ssrc * 64 + c) * 2 + 1];
      float m2 = s2 / 12000.f, v2 = q2 / 12000.f - m2 * m2;
      float r2 = rsqrtf(v2 + 1e-5f);
      float ws;
      float raw = bilin_raw_h(p0 + (size_t)ssrc * cHF * cWF * cC, cHF, cWF, fx, fy, c, ws);
      float featn = (raw - m2 * ws) * r2;
      feat2[t][c] = featn * rstdS * 0.125f;        // 1/sqrt(64) folded
      float bc = featn * (-meanS * rstdS) * 0.125f;
      #pragma unroll
      for (int o = 32; o; o >>= 1) bc += __shfl_xor(bc, o);
      if (c == 0) biasS[t] = bc;
    }
  }
  __syncthreads();

  // ---- gather + 3 dots per 8x8 grid point, bilinear combine -> fcL ----
  {
    int l = tid >> 6, lane = tid & 63;
    const _Float16* Ls[4] = {p0, p1, p2, p3};
    const int Hs[4] = {cHF, 50, 25, 12}, Ws[4] = {cWF, 60, 30, 15};
    float cx = cof_cur[((size_t)s * cN + n) * 2 + 0];
    float cy = cof_cur[((size_t)s * cN + n) * 2 + 1];
    float sc = 1.0f / (float)(1 << l);
    float x = fminf(fmaxf(cx * sc, -2.0e6f), 2.0e6f);
    float y = fminf(fmaxf(cy * sc, -2.0e6f), 2.0e6f);
    float x0f = floorf(x), y0f = floorf(y);
    float wx = x - x0f, wy = y - y0f;
    int dxi = lane & 7, dyi = lane >> 3;
    int ix = (int)x0f + dxi - 3, iy = (int)y0f + dyi - 3;
    int Hl = Hs[l], Wl = Ws[l];
    float d[3] = {0.f, 0.f, 0.f};
    if (ix >= 0 && ix < Wl && iy >= 0 && iy < Hl) {
      const _Float16* row = Ls[l] + (((size_t)s * Hl + iy) * Wl + ix) * cC;
      float a0 = 0.f, a1 = 0.f, a2 = 0.f;
      #pragma unroll
      for (int c8 = 0; c8 < 8; c8++) {
        half8 v = *(const half8*)(row + c8 * 8);
        #pragma unroll
        for (int e = 0; e < 8; e++) {
          float f = (float)v[e];
          a0 += f * feat2[0][c8 * 8 + e];
          a1 += f * feat2[1][c8 * 8 + e];
          a2 += f * feat2[2][c8 * 8 + e];
        }
      }
      d[0] = a0 + biasS[0]; d[1] = a1 + biasS[1]; d[2] = a2 + biasS[2];
    }
    int dy = lane / 7, dx = lane - dy * 7;
    int bb = (lane < 49) ? (dy * 8 + dx) : 0;
    float w00 = (1.f - wy) * (1.f - wx), w01 = (1.f - wy) * wx;
    float w10 = wy * (1.f - wx), w11 = wy * wx;
    #pragma unroll
    for (int t = 0; t < 3; t++) {
      float d00 = __shfl(d[t], bb, 64);
      float d01 = __shfl(d[t], bb + 1, 64);
      float d10 = __shfl(d[t], bb + 8, 64);
      float d11 = __shfl(d[t], bb + 9, 64);
      if (lane < 49)
        fcL[t * 196 + l * 49 + lane] = w00 * d00 + w01 * d01 + w10 * d10 + w11 * d11;
    }
  }
  __syncthreads();

  // ---- phase B: MLP + coords update ----
  int j = tid & 127, half = tid >> 7;
  {
    float h = 0.f;
    int k0 = half * 294;
    const _Float16* Lw = LWc + (size_t)k0 * 128 + j;
    for (int k = 0; k < 294; k++) h += fcL[k0 + k] * (float)Lw[(size_t)k * 128];
    hp[half][j] = h;
  }
  __syncthreads();
  if (half == 0) {
    const float* Wfl = w1t + (size_t)392 * 128;
    const float* Wxy = w1t + (size_t)3394 * 128;
    float xx = xys[n * 2 + 0], yy = xys[n * 2 + 1];
    int sA = min(s + 1, 15), sB = (s == 15) ? 14 : s;
    float flx = cof_cur[(sA * cN + n) * 2 + 0] - cof_cur[(sB * cN + n) * 2 + 0];
    float fly = cof_cur[(sA * cN + n) * 2 + 1] - cof_cur[(sB * cN + n) * 2 + 1];
    float v = hp[0][j] + hp[1][j] + b1e[j] + ffw[s * 128 + j] +
              flx * Wfl[j] + fly * Wfl[128 + j] + xx * Wxy[j] + yy * Wxy[128 + j];
    hl[j] = fmaxf(v, 0.f);
  }
  __syncthreads();
  if (tid < 2) {
    int d = tid;
    float acc = b2[d];
    for (int k = 0; k < 128; k++) acc += hl[k] * w2[k * 2 + d];
    float cc = cof_cur[((size_t)s * cN + n) * 2 + d] + acc;
    cof_nxt[((size_t)s * cN + n) * 2 + d] = cc;
    out[((size_t)s * cN + n) * 2 + d] = cc * 2.0f;
  }
}

// ---------------------------------------------------------------------------
extern "C" void kernel_launch(void* const* d_in, const int* in_sizes, int n_in,
                              void* d_out, int out_size, void* d_ws, size_t ws_size,
                              hipStream_t stream) {
  (void)in_sizes; (void)n_in; (void)out_size; (void)ws_size;
  const float* rgbs = (const float*)d_in[0];
  const float* pts  = (const float*)d_in[1];
  const float* fnw  = (const float*)d_in[2];
  const float* fnfw = (const float*)d_in[3];
  const float* lw   = (const float*)d_in[4];
  const float* lb   = (const float*)d_in[5];
  const float* w1s  = (const float*)d_in[6];
  const float* b1s  = (const float*)d_in[7];
  const float* w2s  = (const float*)d_in[8];
  const float* b2s  = (const float*)d_in[9];
  const float* w1t  = (const float*)d_in[10];
  const float* b1t  = (const float*)d_in[11];
  const float* w2t  = (const float*)d_in[12];
  const float* b2t  = (const float*)d_in[13];
  float* out = (float*)d_out;

  float* p = (float*)d_ws;
  auto alloc = [&](size_t nf) { float* r = p; p += nf; return r; };
  float* part  = alloc((size_t)2 * cS * cNCH * 128);
  float* ffw_s = alloc(cS * 128);
  float* ffw_t = alloc(cS * 128);
  _Float16* LWc = (_Float16*)alloc((size_t)588 * 128 / 2);
  float* b1te  = alloc(128);
  float* fmc   = alloc((size_t)cS * cHC * cWC * cC);
  float* arp   = alloc((size_t)cS * 196 * cC);
  float* partf = alloc((size_t)cS * cHF * cC * 2);
  float* stats = alloc(cS * cC * 2);
  _Float16* fmf = (_Float16*)alloc((size_t)cS * cHF * cWF * cC / 2);
  _Float16* pf1 = (_Float16*)alloc((size_t)cS * 50 * 60 * cC / 2);
  _Float16* pf2 = (_Float16*)alloc((size_t)cS * 25 * 30 * cC / 2);
  _Float16* pf3 = (_Float16*)alloc((size_t)cS * 12 * 15 * cC / 2);
  float* xys0  = alloc(cN * 2);
  float* cofA  = alloc((size_t)cS * cN * 2);
  float* cofB  = alloc((size_t)cS * cN * 2);

  // 1) independent front work
  k_front<<<NB_FFP + NB_CONVC + NB_CONVF, 256, 0, stream>>>(
      rgbs, w1s, w1t, fnw, fnfw, part, fmc, fmf, partf);
  // 2) reductions + precomputes
  k_mid<<<123, 256, 0, stream>>>(part, ffw_s, ffw_t, lw, lb, w1t, b1t, LWc, b1te,
                                 partf, stats, fmc, arp);
  // 3) coarse MLP + fine pyramid (independent roles)
  k_mix<<<464, 256, 0, stream>>>(arp, fmc, w1s, b1s, ffw_s, w2s, b2s, pts,
                                 cofA, xys0, out, fmf, pf1, pf2, pf3);
  // 4-7) fused fine iterations
  float* cbuf[2] = {cofA, cofB};
  for (int it = 0; it < cITERS; it++) {
    float* cur = cbuf[it & 1];
    float* nxt = cbuf[(it & 1) ^ 1];
    k_iter<<<1024, 256, 0, stream>>>(fmf, pf1, pf2, pf3, stats, LWc, b1te, ffw_t,
                                     w1t, w2t, b2t, cur, nxt, xys0,
                                     out + (size_t)(it + 1) * cS * cN * 2);
  }
}